// Round 15
// baseline (48.537 us; speedup 1.0000x reference)
//
#include <hip/hip_runtime.h>
#include <math.h>

namespace {

constexpr int D = 256;
constexpr int H = 8;

typedef __attribute__((ext_vector_type(8))) short bf16x8;
typedef __attribute__((ext_vector_type(4))) float f32x4;

__device__ inline unsigned short bf16rn(float x) {
  unsigned u = __builtin_bit_cast(unsigned, x);
  u += 0x7fffu + ((u >> 16) & 1u);
  return (unsigned short)(u >> 16);
}
__device__ inline float bf16tof(unsigned short b) {
  return __builtin_bit_cast(float, (unsigned)b << 16);
}

// workspace byte offsets
constexpr size_t OFF_QW  = 0;                          // 8 MiB f32 qW
constexpr size_t OFF_WFH = (size_t)8 << 20;            // 1 MiB W-frag hi
constexpr size_t OFF_WFL = (size_t)9 << 20;            // 1 MiB W-frag lo
constexpr size_t OFF_QFH = (size_t)10 << 20;           // 512 KiB q-frag hi
constexpr size_t OFF_QFL = ((size_t)10 << 20) + ((size_t)512 << 10);

// ---------------- Kernel 0: prep — bf16 hi/lo fragments of q and W ----------------
// (byte-identical to R11-R14 — verified)
__global__ __launch_bounds__(256) void prep_kernel(
    const float* __restrict__ q, const float* __restrict__ W,
    char* __restrict__ ws) {
  const int gid = blockIdx.x * 256 + threadIdx.x;
  float e[8];
  char *hi_base, *lo_base;
  size_t outoff;
  if (gid < 65536) {          // blocks 0..255: W part
    const int l = gid & 63, ks = (gid >> 6) & 7, he = gid >> 9;
    const int h = he >> 4, et = he & 15;
    const int d0 = ks * 32 + ((l >> 4) << 3);
    const int ecol = et * 16 + (l & 15);
    const float* src = W + (size_t)h * 65536 + (size_t)d0 * 256 + ecol;
    #pragma unroll
    for (int j = 0; j < 8; ++j) e[j] = src[j * 256];
    hi_base = ws + OFF_WFH; lo_base = ws + OFF_WFL;
    outoff = (size_t)gid * 16;
  } else {                    // blocks 256..383: q part
    const int t = gid - 65536;
    const int l = t & 63, ks = (t >> 6) & 7, bt = t >> 9;
    const int row = bt * 16 + (l & 15);
    const int d0 = ks * 32 + ((l >> 4) << 3);
    const float4* src = reinterpret_cast<const float4*>(q + (size_t)row * 256 + d0);
    float4 a = src[0], b = src[1];
    e[0] = a.x; e[1] = a.y; e[2] = a.z; e[3] = a.w;
    e[4] = b.x; e[5] = b.y; e[6] = b.z; e[7] = b.w;
    hi_base = ws + OFF_QFH; lo_base = ws + OFF_QFL;
    outoff = (size_t)t * 16;
  }
  unsigned hw[4], lw[4];
  #pragma unroll
  for (int p = 0; p < 4; ++p) {
    unsigned short h0 = bf16rn(e[2 * p]), h1 = bf16rn(e[2 * p + 1]);
    unsigned short l0 = bf16rn(e[2 * p] - bf16tof(h0));
    unsigned short l1 = bf16rn(e[2 * p + 1] - bf16tof(h1));
    hw[p] = (unsigned)h0 | ((unsigned)h1 << 16);
    lw[p] = (unsigned)l0 | ((unsigned)l1 << 16);
  }
  *reinterpret_cast<uint4*>(hi_base + outoff) = make_uint4(hw[0], hw[1], hw[2], hw[3]);
  *reinterpret_cast<uint4*>(lo_base + outoff) = make_uint4(lw[0], lw[1], lw[2], lw[3]);
}

// ---------------- Kernel 1: qW via split-bf16 MFMA ----------------
// (byte-identical to R11-R14 — verified; keeps f32-grade qW)
__global__ __launch_bounds__(256) void qw_mfma_kernel(
    const char* __restrict__ ws_in, float* __restrict__ qW) {
  const int tid = threadIdx.x;
  const int w   = blockIdx.x * 4 + (tid >> 6);
  const int l   = tid & 63;
  const int bng = w >> 5;
  const int heg = w & 31;
  const char* qfh = ws_in + OFF_QFH;
  const char* qfl = ws_in + OFF_QFL;
  const char* wfh = ws_in + OFF_WFH;
  const char* wfl = ws_in + OFF_WFL;

  f32x4 acc[2][4];
  #pragma unroll
  for (int i = 0; i < 2; ++i)
    #pragma unroll
    for (int j = 0; j < 4; ++j) acc[i][j] = {0.f, 0.f, 0.f, 0.f};

  #pragma unroll 2
  for (int ks = 0; ks < 8; ++ks) {
    bf16x8 aH[2], aL[2], bH[4], bL[4];
    #pragma unroll
    for (int i = 0; i < 2; ++i) {
      const size_t off = ((size_t)((bng * 2 + i) * 8 + ks) * 64 + l) * 16;
      aH[i] = *reinterpret_cast<const bf16x8*>(qfh + off);
      aL[i] = *reinterpret_cast<const bf16x8*>(qfl + off);
    }
    #pragma unroll
    for (int j = 0; j < 4; ++j) {
      const size_t off = ((size_t)((heg * 4 + j) * 8 + ks) * 64 + l) * 16;
      bH[j] = *reinterpret_cast<const bf16x8*>(wfh + off);
      bL[j] = *reinterpret_cast<const bf16x8*>(wfl + off);
    }
    #pragma unroll
    for (int i = 0; i < 2; ++i)
      #pragma unroll
      for (int j = 0; j < 4; ++j) {
        acc[i][j] = __builtin_amdgcn_mfma_f32_16x16x32_bf16(aH[i], bH[j], acc[i][j], 0, 0, 0);
        acc[i][j] = __builtin_amdgcn_mfma_f32_16x16x32_bf16(aH[i], bL[j], acc[i][j], 0, 0, 0);
        acc[i][j] = __builtin_amdgcn_mfma_f32_16x16x32_bf16(aL[i], bH[j], acc[i][j], 0, 0, 0);
      }
  }

  const int rbase = (l >> 4) * 4;
  const int col   = l & 15;
  #pragma unroll
  for (int i = 0; i < 2; ++i)
    #pragma unroll
    for (int j = 0; j < 4; ++j) {
      const size_t cidx = (size_t)(heg * 4 + j) * 16 + col;
      #pragma unroll
      for (int r = 0; r < 4; ++r) {
        const int bn = (bng * 2 + i) * 16 + rbase + r;
        qW[(size_t)bn * 2048 + cidx] = acc[i][j][r];
      }
    }
}

// ---------------- Kernel 2: fused scores+softmax+PV — wave-autonomous, 0 barriers --
// Grid 256 x 256 thr = 1024 waves; wave = one bn, fully self-contained.
// Per-wave private LDS slice: B-hi frags (8320 B) + wsum (256 B). All LDS
// producer/consumer pairs are within one wave -> lgkmcnt only, NO __syncthreads.
// Tiles T=0..3 processed serially: 16-deep k-frag load burst (A-direct, R14-verified
// fragment addressing) -> convert -> 8 MFMA -> wave-local softmax (chunks 2T,2T+1)
// -> attn write; wsum accumulated in registers across tiles. PV: 4 x 16-deep v
// bursts, direct float4 out write (wave owns the full 256-d row).
constexpr int WAVE_LDS = 8576;   // 8320 B-frag + 256 wsum

__global__ __attribute__((amdgpu_waves_per_eu(1, 4))) __launch_bounds__(256)
void attn_fused_kernel(
    const float* __restrict__ qW, const float* __restrict__ kin,
    const float* __restrict__ vin, const float* __restrict__ bin,
    float* __restrict__ out, float* __restrict__ attn_out) {
  __shared__ alignas(16) char sm_all[4][WAVE_LDS];
  const int tid = threadIdx.x;
  const int wid = tid >> 6;
  const int ln  = tid & 63;
  const int bn  = blockIdx.x * 4 + wid;
  char* sm = sm_all[wid];
  float* wsum_l = reinterpret_cast<float*>(sm + 8320);

  // ---- B-frags: 8 coalesced qW loads (issued as a batch), convert, LDS write
  const float4* qw4 = reinterpret_cast<const float4*>(qW) + (size_t)bn * 512;
  float4 qv[8];
  #pragma unroll
  for (int i = 0; i < 8; ++i) qv[i] = qw4[i * 64 + ln];
  #pragma unroll
  for (int t = 0; t < 4; ++t) {   // zero-fill cols 8-15 slots
    int z = t * 64 + ln;
    int ks = z >> 5, slot = 32 + (z & 31);
    *reinterpret_cast<uint4*>(sm + ks * 1040 + slot * 16) = make_uint4(0u, 0u, 0u, 0u);
  }
  {
    const int ks = ln >> 3, g = (ln >> 1) & 3, j0 = (ln & 1) * 4;
    #pragma unroll
    for (int i = 0; i < 8; ++i) {     // slot hh = i (R13/R14-verified placement)
      int base = ks * 1040 + (i * 4 + g) * 16 + j0 * 2;
      unsigned short h0 = bf16rn(qv[i].x), h1 = bf16rn(qv[i].y),
                     h2 = bf16rn(qv[i].z), h3 = bf16rn(qv[i].w);
      *reinterpret_cast<uint2*>(sm + base) =
          make_uint2((unsigned)h0 | ((unsigned)h1 << 16),
                     (unsigned)h2 | ((unsigned)h3 << 16));
    }
  }

  const float bias = bin[ln & 7];
  const int col = ln & 15;
  const bool valid = col < 8;
  const int slot_r = (ln & 15) * 4 + (ln >> 4);
  const char* pbH = sm + slot_r * 16;
  const float* kbase = kin + (size_t)bn * 16384 +
                       (size_t)(ln & 15) * 256 + ((ln >> 4) << 3);

  float wa0 = 0.f, wa1 = 0.f, wa2 = 0.f, wa3 = 0.f;   // wsum reg accumulators

  for (int T = 0; T < 4; ++T) {
    // ---- A-direct k-frag burst: 16 independent float4 loads
    const float* arow = kbase + T * 16 * 256;
    float4 ka[16];
    #pragma unroll
    for (int ks = 0; ks < 8; ++ks) {
      ka[2 * ks]     = *reinterpret_cast<const float4*>(arow + ks * 32);
      ka[2 * ks + 1] = *reinterpret_cast<const float4*>(arow + ks * 32 + 4);
    }
    // ---- convert + MFMA over K=256
    f32x4 acc = {0.f, 0.f, 0.f, 0.f};
    #pragma unroll
    for (int ks = 0; ks < 8; ++ks) {
      const float4 a0 = ka[2 * ks], a1 = ka[2 * ks + 1];
      bf16x8 aH;
      aH[0] = (short)bf16rn(a0.x); aH[1] = (short)bf16rn(a0.y);
      aH[2] = (short)bf16rn(a0.z); aH[3] = (short)bf16rn(a0.w);
      aH[4] = (short)bf16rn(a1.x); aH[5] = (short)bf16rn(a1.y);
      aH[6] = (short)bf16rn(a1.z); aH[7] = (short)bf16rn(a1.w);
      bf16x8 bH = *reinterpret_cast<const bf16x8*>(pbH + ks * 1040);
      acc = __builtin_amdgcn_mfma_f32_16x16x32_bf16(aH, bH, acc, 0, 0, 0);
    }
    // ---- wave-local softmax (chunks 2T, 2T+1) — R14-verified reduce
    float x0 = acc[0] + bias, x1 = acc[1] + bias, x2 = acc[2] + bias, x3 = acc[3] + bias;
    float m = valid ? fmaxf(fmaxf(x0, x1), fmaxf(x2, x3)) : -1e30f;
    m = fmaxf(m, __shfl_xor(m, 1, 64));
    m = fmaxf(m, __shfl_xor(m, 2, 64));
    m = fmaxf(m, __shfl_xor(m, 4, 64));
    m = fmaxf(m, __shfl_xor(m, 16, 64));
    float e0 = valid ? expf(x0 - m) : 0.f;
    float e1 = valid ? expf(x1 - m) : 0.f;
    float e2 = valid ? expf(x2 - m) : 0.f;
    float e3 = valid ? expf(x3 - m) : 0.f;
    float s = e0 + e1 + e2 + e3;
    s += __shfl_xor(s, 1, 64);
    s += __shfl_xor(s, 2, 64);
    s += __shfl_xor(s, 4, 64);
    s += __shfl_xor(s, 16, 64);
    float inv = 1.f / s;
    float p0 = e0 * inv, p1 = e1 * inv, p2 = e2 * inv, p3 = e3 * inv;
    if (valid) {
      size_t base = (size_t)bn * 512 + (size_t)(T * 16 + (ln >> 4) * 4) * 8 + col;
      attn_out[base]      = p0;
      attn_out[base + 8]  = p1;
      attn_out[base + 16] = p2;
      attn_out[base + 24] = p3;
    }
    // wsum: chunk-pair sum via xor-32, accumulate in regs across tiles
    p0 += __shfl_xor(p0, 32, 64);
    p1 += __shfl_xor(p1, 32, 64);
    p2 += __shfl_xor(p2, 32, 64);
    p3 += __shfl_xor(p3, 32, 64);
    wa0 += p0; wa1 += p1; wa2 += p2; wa3 += p3;
  }

  // ---- store wsum (16 writer lanes, pos=(rb+r)*8+c8) — wave-local
  if (ln < 32 && (ln & 15) < 8) {
    const int rb = (ln >> 4) * 4;
    const int c8 = ln & 7;
    wsum_l[(rb + 0) * 8 + c8] = wa0;
    wsum_l[(rb + 1) * 8 + c8] = wa1;
    wsum_l[(rb + 2) * 8 + c8] = wa2;
    wsum_l[(rb + 3) * 8 + c8] = wa3;
  }

  // ---- PV: 4 bursts of 16 independent coalesced v loads
  const float4* v4 = reinterpret_cast<const float4*>(vin) + (size_t)bn * 4096;
  float4 av = make_float4(0.f, 0.f, 0.f, 0.f);
  #pragma unroll
  for (int rb = 0; rb < 4; ++rb) {
    float4 vv[16];
    #pragma unroll
    for (int i = 0; i < 16; ++i) vv[i] = v4[(size_t)(rb * 16 + i) * 64 + ln];
    #pragma unroll
    for (int i = 0; i < 16; ++i) {
      float w = wsum_l[rb * 16 + i];
      av.x += w * vv[i].x; av.y += w * vv[i].y;
      av.z += w * vv[i].z; av.w += w * vv[i].w;
    }
  }
  *reinterpret_cast<float4*>(&out[(size_t)bn * D + ln * 4]) = av;
}

}  // namespace

extern "C" void kernel_launch(void* const* d_in, const int* in_sizes, int n_in,
                              void* d_out, int out_size, void* d_ws, size_t ws_size,
                              hipStream_t stream) {
  const float* q = (const float*)d_in[0];   // (8,128,1,256)
  const float* k = (const float*)d_in[1];   // (8,128,64,256)
  const float* v = (const float*)d_in[2];   // (8,128,64,256)
  const float* W = (const float*)d_in[3];   // (8,256,256)
  const float* b = (const float*)d_in[4];   // (8,)

  float* out  = (float*)d_out;              // output: 262144 f32
  float* attn = out + 262144;               // attn:   524288 f32
  char*  ws   = (char*)d_ws;
  float* qWbuf = (float*)(ws + OFF_QW);     // 8 MiB f32 qW

  hipLaunchKernelGGL(prep_kernel,       dim3(384), dim3(256), 0, stream, q, W, ws);
  hipLaunchKernelGGL(qw_mfma_kernel,    dim3(256), dim3(256), 0, stream, ws, qWbuf);
  hipLaunchKernelGGL(attn_fused_kernel, dim3(256), dim3(256), 0, stream,
                     qWbuf, k, v, b, out, attn);
}

// Round 16
// 44.206 us; speedup vs baseline: 1.0980x; 1.0980x over previous
//
#include <hip/hip_runtime.h>
#include <math.h>

namespace {

constexpr int D = 256;
constexpr int H = 8;

typedef __attribute__((ext_vector_type(8))) short bf16x8;
typedef __attribute__((ext_vector_type(4))) float f32x4;

__device__ inline unsigned short bf16rn(float x) {
  unsigned u = __builtin_bit_cast(unsigned, x);
  u += 0x7fffu + ((u >> 16) & 1u);
  return (unsigned short)(u >> 16);
}
__device__ inline float bf16tof(unsigned short b) {
  return __builtin_bit_cast(float, (unsigned)b << 16);
}

// workspace byte offsets
constexpr size_t OFF_QW  = 0;                          // 8 MiB f32 qW
constexpr size_t OFF_WFH = (size_t)8 << 20;            // 1 MiB W-frag hi
constexpr size_t OFF_WFL = (size_t)9 << 20;            // 1 MiB W-frag lo
constexpr size_t OFF_QFH = (size_t)10 << 20;           // 512 KiB q-frag hi
constexpr size_t OFF_QFL = ((size_t)10 << 20) + ((size_t)512 << 10);

// ---------------- Kernel 0: prep — bf16 hi/lo fragments of q and W ----------------
// (byte-identical to R11-R15 — verified)
__global__ __launch_bounds__(256) void prep_kernel(
    const float* __restrict__ q, const float* __restrict__ W,
    char* __restrict__ ws) {
  const int gid = blockIdx.x * 256 + threadIdx.x;
  float e[8];
  char *hi_base, *lo_base;
  size_t outoff;
  if (gid < 65536) {          // blocks 0..255: W part
    const int l = gid & 63, ks = (gid >> 6) & 7, he = gid >> 9;
    const int h = he >> 4, et = he & 15;
    const int d0 = ks * 32 + ((l >> 4) << 3);
    const int ecol = et * 16 + (l & 15);
    const float* src = W + (size_t)h * 65536 + (size_t)d0 * 256 + ecol;
    #pragma unroll
    for (int j = 0; j < 8; ++j) e[j] = src[j * 256];
    hi_base = ws + OFF_WFH; lo_base = ws + OFF_WFL;
    outoff = (size_t)gid * 16;
  } else {                    // blocks 256..383: q part
    const int t = gid - 65536;
    const int l = t & 63, ks = (t >> 6) & 7, bt = t >> 9;
    const int row = bt * 16 + (l & 15);
    const int d0 = ks * 32 + ((l >> 4) << 3);
    const float4* src = reinterpret_cast<const float4*>(q + (size_t)row * 256 + d0);
    float4 a = src[0], b = src[1];
    e[0] = a.x; e[1] = a.y; e[2] = a.z; e[3] = a.w;
    e[4] = b.x; e[5] = b.y; e[6] = b.z; e[7] = b.w;
    hi_base = ws + OFF_QFH; lo_base = ws + OFF_QFL;
    outoff = (size_t)t * 16;
  }
  unsigned hw[4], lw[4];
  #pragma unroll
  for (int p = 0; p < 4; ++p) {
    unsigned short h0 = bf16rn(e[2 * p]), h1 = bf16rn(e[2 * p + 1]);
    unsigned short l0 = bf16rn(e[2 * p] - bf16tof(h0));
    unsigned short l1 = bf16rn(e[2 * p + 1] - bf16tof(h1));
    hw[p] = (unsigned)h0 | ((unsigned)h1 << 16);
    lw[p] = (unsigned)l0 | ((unsigned)l1 << 16);
  }
  *reinterpret_cast<uint4*>(hi_base + outoff) = make_uint4(hw[0], hw[1], hw[2], hw[3]);
  *reinterpret_cast<uint4*>(lo_base + outoff) = make_uint4(lw[0], lw[1], lw[2], lw[3]);
}

// ---------------- Kernel 1: qW via split-bf16 MFMA ----------------
// (byte-identical to R11-R15 — verified; keeps f32-grade qW)
__global__ __launch_bounds__(256) void qw_mfma_kernel(
    const char* __restrict__ ws_in, float* __restrict__ qW) {
  const int tid = threadIdx.x;
  const int w   = blockIdx.x * 4 + (tid >> 6);
  const int l   = tid & 63;
  const int bng = w >> 5;
  const int heg = w & 31;
  const char* qfh = ws_in + OFF_QFH;
  const char* qfl = ws_in + OFF_QFL;
  const char* wfh = ws_in + OFF_WFH;
  const char* wfl = ws_in + OFF_WFL;

  f32x4 acc[2][4];
  #pragma unroll
  for (int i = 0; i < 2; ++i)
    #pragma unroll
    for (int j = 0; j < 4; ++j) acc[i][j] = {0.f, 0.f, 0.f, 0.f};

  #pragma unroll 2
  for (int ks = 0; ks < 8; ++ks) {
    bf16x8 aH[2], aL[2], bH[4], bL[4];
    #pragma unroll
    for (int i = 0; i < 2; ++i) {
      const size_t off = ((size_t)((bng * 2 + i) * 8 + ks) * 64 + l) * 16;
      aH[i] = *reinterpret_cast<const bf16x8*>(qfh + off);
      aL[i] = *reinterpret_cast<const bf16x8*>(qfl + off);
    }
    #pragma unroll
    for (int j = 0; j < 4; ++j) {
      const size_t off = ((size_t)((heg * 4 + j) * 8 + ks) * 64 + l) * 16;
      bH[j] = *reinterpret_cast<const bf16x8*>(wfh + off);
      bL[j] = *reinterpret_cast<const bf16x8*>(wfl + off);
    }
    #pragma unroll
    for (int i = 0; i < 2; ++i)
      #pragma unroll
      for (int j = 0; j < 4; ++j) {
        acc[i][j] = __builtin_amdgcn_mfma_f32_16x16x32_bf16(aH[i], bH[j], acc[i][j], 0, 0, 0);
        acc[i][j] = __builtin_amdgcn_mfma_f32_16x16x32_bf16(aH[i], bL[j], acc[i][j], 0, 0, 0);
        acc[i][j] = __builtin_amdgcn_mfma_f32_16x16x32_bf16(aL[i], bH[j], acc[i][j], 0, 0, 0);
      }
  }

  const int rbase = (l >> 4) * 4;
  const int col   = l & 15;
  #pragma unroll
  for (int i = 0; i < 2; ++i)
    #pragma unroll
    for (int j = 0; j < 4; ++j) {
      const size_t cidx = (size_t)(heg * 4 + j) * 16 + col;
      #pragma unroll
      for (int r = 0; r < 4; ++r) {
        const int bn = (bng * 2 + i) * 16 + rbase + r;
        qW[(size_t)bn * 2048 + cidx] = acc[i][j][r];
      }
    }
}

// ---------------- Kernel 2: fused scores+softmax+PV (R14 + pinned load batches) ---
// Per-bn block (1024), 4 waves, wave = tile T=wid. Deltas vs R14 (verified):
// (a) ALL loads (16 ka + 2 qW + 16 v) issued at kernel start, each batch pinned
//     with sched_barrier(0) so the compiler cannot sink them (R14/R15 showed
//     VGPR=32/68 = sunk loads = serial vmcnt chains); 34 loads in flight/wave.
// (b) __launch_bounds__(256,2): VGPR budget 256, 2 blocks/CU = 8 waves/CU.
// Everything downstream byte-identical to R14.
constexpr int FB2   = 0;
constexpr int WSP2  = 8320;
constexpr int SMEM3 = 9344;

__global__ __launch_bounds__(256, 2) void attn_fused_kernel(
    const float* __restrict__ qW, const float* __restrict__ kin,
    const float* __restrict__ vin, const float* __restrict__ bin,
    float* __restrict__ out, float* __restrict__ attn_out) {
  __shared__ alignas(16) long long smem_ll[SMEM3 / 8];
  char* sm = reinterpret_cast<char*>(smem_ll);
  float* wsp = reinterpret_cast<float*>(sm + WSP2);   // flat [4*64]
  const int tid = threadIdx.x;
  const int bn  = blockIdx.x;
  const int wid = tid >> 6;
  const int ln  = tid & 63;

  // ---- batch 1: A-direct k-frag loads (16 independent float4), pinned
  const float* arow = kin + (size_t)bn * 16384 +
                      (size_t)(wid * 16 + (ln & 15)) * 256 + ((ln >> 4) << 3);
  float4 ka[16];
  #pragma unroll
  for (int ks = 0; ks < 8; ++ks) {
    ka[2 * ks]     = *reinterpret_cast<const float4*>(arow + ks * 32);
    ka[2 * ks + 1] = *reinterpret_cast<const float4*>(arow + ks * 32 + 4);
  }
  __builtin_amdgcn_sched_barrier(0);

  // ---- batch 2: qW loads, pinned
  const float4* qw4 = reinterpret_cast<const float4*>(qW) + (size_t)bn * 512;
  float4 qv0 = qw4[tid];
  float4 qv1 = qw4[tid + 256];
  __builtin_amdgcn_sched_barrier(0);

  // ---- batch 3: v loads (16 independent, coalesced), pinned — consumed last
  const float4* v4 = reinterpret_cast<const float4*>(vin) + (size_t)bn * 4096;
  float4 vv[16];
  #pragma unroll
  for (int i = 0; i < 16; ++i) vv[i] = v4[(size_t)(wid + 4 * i) * 64 + ln];
  __builtin_amdgcn_sched_barrier(0);

  // ---- zero-fill unwritten B slots (cols 8-15)
  {
    const int ks = tid >> 5, slot = 32 + (tid & 31);
    *reinterpret_cast<uint4*>(sm + FB2 + ks * 1040 + slot * 16) =
        make_uint4(0u, 0u, 0u, 0u);
  }
  // ---- qW -> B-hi frags (R13/R14-verified placement)
  #pragma unroll
  for (int i = 0; i < 2; ++i) {
    int p = tid + 256 * i;
    int hh = p >> 6, equad = p & 63;
    int ks = equad >> 3, g = (equad >> 1) & 3, j0 = (equad & 1) * 4;
    int base = FB2 + ks * 1040 + (hh * 4 + g) * 16 + j0 * 2;
    float4 qv = i == 0 ? qv0 : qv1;
    unsigned short h0 = bf16rn(qv.x), h1 = bf16rn(qv.y),
                   h2 = bf16rn(qv.z), h3 = bf16rn(qv.w);
    *reinterpret_cast<uint2*>(sm + base) =
        make_uint2((unsigned)h0 | ((unsigned)h1 << 16),
                   (unsigned)h2 | ((unsigned)h3 << 16));
  }
  __syncthreads();

  // ---- MFMA over full K=256, tile T = wid (converts ka in registers)
  const int slot_r = (ln & 15) * 4 + (ln >> 4);
  const char* pbH = sm + FB2 + slot_r * 16;
  f32x4 acc = {0.f, 0.f, 0.f, 0.f};
  #pragma unroll
  for (int ks = 0; ks < 8; ++ks) {
    const float4 a0 = ka[2 * ks], a1 = ka[2 * ks + 1];
    bf16x8 aH;
    aH[0] = (short)bf16rn(a0.x); aH[1] = (short)bf16rn(a0.y);
    aH[2] = (short)bf16rn(a0.z); aH[3] = (short)bf16rn(a0.w);
    aH[4] = (short)bf16rn(a1.x); aH[5] = (short)bf16rn(a1.y);
    aH[6] = (short)bf16rn(a1.z); aH[7] = (short)bf16rn(a1.w);
    bf16x8 bH = *reinterpret_cast<const bf16x8*>(pbH + ks * 1040);
    acc = __builtin_amdgcn_mfma_f32_16x16x32_bf16(aH, bH, acc, 0, 0, 0);
  }

  // ---- softmax on C-frags (chunk = 2*wid + (ln>=32); R14-verified reduce)
  const float bias = bin[ln & 7];
  const int col = ln & 15;
  const bool valid = col < 8;
  float x0 = acc[0] + bias, x1 = acc[1] + bias, x2 = acc[2] + bias, x3 = acc[3] + bias;
  float m = valid ? fmaxf(fmaxf(x0, x1), fmaxf(x2, x3)) : -1e30f;
  m = fmaxf(m, __shfl_xor(m, 1, 64));
  m = fmaxf(m, __shfl_xor(m, 2, 64));
  m = fmaxf(m, __shfl_xor(m, 4, 64));
  m = fmaxf(m, __shfl_xor(m, 16, 64));
  float e0 = valid ? expf(x0 - m) : 0.f;
  float e1 = valid ? expf(x1 - m) : 0.f;
  float e2 = valid ? expf(x2 - m) : 0.f;
  float e3 = valid ? expf(x3 - m) : 0.f;
  float s = e0 + e1 + e2 + e3;
  s += __shfl_xor(s, 1, 64);
  s += __shfl_xor(s, 2, 64);
  s += __shfl_xor(s, 4, 64);
  s += __shfl_xor(s, 16, 64);
  float inv = 1.f / s;
  float p0 = e0 * inv, p1 = e1 * inv, p2 = e2 * inv, p3 = e3 * inv;
  if (valid) {
    size_t base = (size_t)bn * 512 + (size_t)(wid * 16 + (ln >> 4) * 4) * 8 + col;
    attn_out[base]      = p0;
    attn_out[base + 8]  = p1;
    attn_out[base + 16] = p2;
    attn_out[base + 24] = p3;
  }
  // wsum partial: pos=(row&7)*8+col, chunk-pair sum via xor-32; one writer/pos.
  p0 += __shfl_xor(p0, 32, 64);
  p1 += __shfl_xor(p1, 32, 64);
  p2 += __shfl_xor(p2, 32, 64);
  p3 += __shfl_xor(p3, 32, 64);
  if (ln < 32 && (ln & 15) < 8) {
    const int rb = (ln >> 4) * 4;
    const int c8 = ln & 7;
    float* w = wsp + wid * 64;
    w[(rb + 0) * 8 + c8] = p0;
    w[(rb + 1) * 8 + c8] = p1;
    w[(rb + 2) * 8 + c8] = p2;
    w[(rb + 3) * 8 + c8] = p3;
  }
  __syncthreads();

  // ---- PV from pre-loaded vv; wsum via broadcast LDS reads
  float4 av = make_float4(0.f, 0.f, 0.f, 0.f);
  #pragma unroll
  for (int i = 0; i < 16; ++i) {
    const int r = wid + 4 * i;
    float w = wsp[r] + wsp[64 + r] + wsp[128 + r] + wsp[192 + r];
    av.x += w * vv[i].x; av.y += w * vv[i].y;
    av.z += w * vv[i].z; av.w += w * vv[i].w;
  }
  float* s_red = reinterpret_cast<float*>(sm);   // [4][260] alias on dead B-frag area
  *reinterpret_cast<float4*>(&s_red[wid * 260 + (ln << 2)]) = av;
  __syncthreads();

  out[(size_t)bn * D + tid] =
      s_red[tid] + s_red[260 + tid] + s_red[520 + tid] + s_red[780 + tid];
}

}  // namespace

extern "C" void kernel_launch(void* const* d_in, const int* in_sizes, int n_in,
                              void* d_out, int out_size, void* d_ws, size_t ws_size,
                              hipStream_t stream) {
  const float* q = (const float*)d_in[0];   // (8,128,1,256)
  const float* k = (const float*)d_in[1];   // (8,128,64,256)
  const float* v = (const float*)d_in[2];   // (8,128,64,256)
  const float* W = (const float*)d_in[3];   // (8,256,256)
  const float* b = (const float*)d_in[4];   // (8,)

  float* out  = (float*)d_out;              // output: 262144 f32
  float* attn = out + 262144;               // attn:   524288 f32
  char*  ws   = (char*)d_ws;
  float* qWbuf = (float*)(ws + OFF_QW);     // 8 MiB f32 qW

  hipLaunchKernelGGL(prep_kernel,       dim3(384),  dim3(256), 0, stream, q, W, ws);
  hipLaunchKernelGGL(qw_mfma_kernel,    dim3(256),  dim3(256), 0, stream, ws, qWbuf);
  hipLaunchKernelGGL(attn_fused_kernel, dim3(1024), dim3(256), 0, stream,
                     qWbuf, k, v, b, out, attn);
}